// Round 18
// baseline (515.000 us; speedup 1.0000x reference)
//
#include <hip/hip_runtime.h>
#include <hip/hip_bf16.h>

#define NN 50000
#define EE 800000
#define GG 64
#define PCH 16   // pooling chunks per graph
#define SCB ((NN + 255) / 256)   // 196 node blocks
// D=128, H=8, C=16, L=3

typedef __attribute__((ext_vector_type(8)))  short          s16x8;
typedef __attribute__((ext_vector_type(8)))  unsigned short u16x8;
typedef __attribute__((ext_vector_type(16))) float          f32x16;

// bf16 helpers (bit-pattern based)
union BFU { __hip_bfloat16 h; unsigned short u; };
__device__ __forceinline__ unsigned short f2bf(float f) {
    BFU b; b.h = __float2bfloat16(f); return b.u;
}
#define B2F_LO(u) __uint_as_float((u) << 16)
#define B2F_HI(u) __uint_as_float((u) & 0xffff0000u)
#define BF2F(us)  __uint_as_float(((unsigned)(us)) << 16)

// packed 2xbf16 dot with f32 accumulate: D = a.lo*b.lo + a.hi*b.hi + c
__device__ __forceinline__ float dot2bf(unsigned a, unsigned b, float c) {
    float r;
    asm("v_dot2_f32_bf16 %0, %1, %2, %3" : "=v"(r) : "v"(a), "v"(b), "v"(c));
    return r;
}

// ---------------------------------------------------------------- CSR build
__global__ __launch_bounds__(256) void hist_kernel(const int* __restrict__ dst,
                                                   int* __restrict__ counts) {
    int e = blockIdx.x * 256 + threadIdx.x;
    if (e < EE) atomicAdd(&counts[dst[e]], 1);
}

// Single-kernel offsets build: per-block LDS scan + one atomicAdd block-base
// reservation (offsets need not be monotone in node id). Folds in starts.
__global__ __launch_bounds__(256)
void node_prep(const int* __restrict__ counts, int* __restrict__ offsets,
               int* __restrict__ gcur,
               const int* __restrict__ batch, int* __restrict__ starts) {
    __shared__ int sm[256];
    __shared__ int base;
    const int t = threadIdx.x;
    const int i = blockIdx.x * 256 + t;
    const int v = (i < NN) ? counts[i] : 0;
    sm[t] = v;
    __syncthreads();
    for (int off = 1; off < 256; off <<= 1) {
        int val = (t >= off) ? sm[t - off] : 0;
        __syncthreads();
        sm[t] += val;
        __syncthreads();
    }
    if (t == 255) base = atomicAdd(gcur, sm[255]);   // reserve contiguous chunk
    __syncthreads();
    if (i < NN) offsets[i] = base + sm[t] - v;       // exclusive within block
    if (i <= NN) {
        int b  = (i < NN) ? batch[i] : GG;
        int bp = (i == 0) ? -1 : batch[i - 1];
        for (int g = bp + 1; g <= b && g <= GG; ++g) starts[g] = i;
    }
}

__global__ __launch_bounds__(256) void scatter_kernel(const int* __restrict__ src,
                                                      const int* __restrict__ dst,
                                                      const int* __restrict__ offs,
                                                      int* __restrict__ cursor,
                                                      int* __restrict__ csrc) {
    int e = blockIdx.x * 256 + threadIdx.x;
    if (e < EE) {
        int dn = dst[e];
        int p = atomicAdd(&cursor[dn], 1);
        csrc[offs[dn] + p] = src[e];
    }
}

// r18: sort each node's edge segment by src id. All resident attn blocks then
// sweep src space low->high in near-lockstep -> instantaneous kv working set
// is a narrow src window (L2/L3-resident) instead of the full 25.6MB.
// Per-node order change only affects fp rounding (threshold headroom 2.6x).
__global__ __launch_bounds__(256)
void sort_edges(const int* __restrict__ offs, const int* __restrict__ cnts,
                int* __restrict__ csrc) {
    const int n = blockIdx.x * 256 + threadIdx.x;
    if (n >= NN) return;
    const int base = offs[n], c = cnts[n];
    for (int i = 1; i < c; ++i) {          // insertion sort (deg ~16, max ~45)
        const int key = csrc[base + i];
        int j = i - 1;
        while (j >= 0 && csrc[base + j] > key) {
            csrc[base + j + 1] = csrc[base + j];
            --j;
        }
        csrc[base + j + 1] = key;
    }
}

// ---------------------------------------------------------------- weight prep
// W[l][k][c] fp32 -> B-FRAGMENT-ORDER split-bf16:
//   wf[mat][(kk*128 + col)*8 + j] = W[kk*8 + j][col],  kk = K-chunk 0..15.
__global__ __launch_bounds__(256)
void prep_weights(const float* __restrict__ Wq, const float* __restrict__ Wk,
                  const float* __restrict__ Wv, const float* __restrict__ Ws,
                  unsigned short* __restrict__ wfh, unsigned short* __restrict__ wfl) {
    const int mat = blockIdx.x;           // 0..11
    const int l = mat >> 2, m = mat & 3;
    const float* W;
    switch (m) {
        case 0:  W = Wq; break;
        case 1:  W = Wk; break;
        case 2:  W = Wv; break;
        default: W = Ws; break;
    }
    W += (size_t)l * 16384;
    const int t = threadIdx.x;
    const int col = blockIdx.y * 16 + (t >> 4);
    const int kk  = t & 15;               // chunk of 8 K values
    u16x8 hi, lo;
    #pragma unroll
    for (int j = 0; j < 8; ++j) {
        float w = W[(kk * 8 + j) * 128 + col];
        unsigned short uh = f2bf(w);
        hi[j] = uh;
        lo[j] = f2bf(w - BF2F(uh));
    }
    const size_t o = (size_t)mat * 16384 + ((size_t)kk * 128 + col) * 8;
    *(u16x8*)(wfh + o) = hi;
    *(u16x8*)(wfl + o) = lo;
}

// ---------------------------------------------------------------- MFMA GEMM
// r15 structure (measured best). 64-node tiles, one barrier, B-frags stream
// from L2 in fragment order. Q (3-term, bf16 out), K+V interleaved (1-term
// each), S (3-term, fp32 out).
__global__ __launch_bounds__(256)
void gemm_mfma(const float* __restrict__ xin,
               const unsigned short* __restrict__ wHg,   // + l*4*16384, frag order
               const unsigned short* __restrict__ wLg,
               const float* __restrict__ bq, const float* __restrict__ bk,
               const float* __restrict__ bv, const float* __restrict__ bs,
               unsigned short* __restrict__ qbf, unsigned short* __restrict__ kvb,
               float* __restrict__ xs) {
    __shared__ unsigned short xl[16384];   // [0..8191]=hi, [8192..]=lo
    const int t = threadIdx.x;
    const int n0 = blockIdx.x * 64;

    // ---- stage x (fp32 -> split bf16, swizzled) ----
    const float4* X4 = (const float4*)xin;
    for (int i = t; i < 1024; i += 256) {            // 64 rows x 16 chunks
        const int row = i >> 4, ch = i & 15;
        const int node = n0 + row;
        float4 fa = make_float4(0.f, 0.f, 0.f, 0.f);
        float4 fb = make_float4(0.f, 0.f, 0.f, 0.f);
        if (node < NN) { fa = X4[node * 32 + ch * 2]; fb = X4[node * 32 + ch * 2 + 1]; }
        const float fv[8] = {fa.x, fa.y, fa.z, fa.w, fb.x, fb.y, fb.z, fb.w};
        u16x8 hi, lo;
        #pragma unroll
        for (int j = 0; j < 8; ++j) {
            unsigned short uh = f2bf(fv[j]);
            hi[j] = uh;
            lo[j] = f2bf(fv[j] - BF2F(uh));
        }
        const int base = row * 128 + (ch ^ (row & 7)) * 8;
        *(u16x8*)&xl[base] = hi;
        *(u16x8*)&xl[8192 + base] = lo;
    }
    __syncthreads();

    // ---- per-wave tile & A-fragments ----
    const int lane = t & 63, wid = t >> 6;
    const int r = lane & 31, g = lane >> 5;
    const int nt = (wid & 1) * 32;        // node offset in tile
    const int cb = (wid >> 1) * 64;       // col base
    s16x8 ah[8], al[8];
    {
        const int row = nt + r;
        const int s = row & 7;
        const int rb = row * 128;
        #pragma unroll
        for (int kc = 0; kc < 8; ++kc) {
            const int idx = rb + (((kc << 1) | g) ^ s) * 8;
            ah[kc] = *(const s16x8*)&xl[idx];
            al[kc] = *(const s16x8*)&xl[8192 + idx];
        }
    }
    const int col0 = cb + r, col1 = cb + 32 + r;

    // ---- phase Q (bf16 out) and phase S (fp32 out), 3-term split-bf16 ----
    #pragma unroll
    for (int pm = 0; pm < 2; ++pm) {
        const int m = pm ? 3 : 0;
        const unsigned short* WH = wHg + m * 16384;
        const unsigned short* WL = wLg + m * 16384;
        f32x16 acc0, acc1;
        #pragma unroll
        for (int j = 0; j < 16; ++j) { acc0[j] = 0.f; acc1[j] = 0.f; }
        #pragma unroll
        for (int kc = 0; kc < 8; ++kc) {
            const int kk = (kc << 1) | g;
            const s16x8 b0 = *(const s16x8*)&WH[(kk * 128 + col0) * 8];
            const s16x8 b1 = *(const s16x8*)&WH[(kk * 128 + col1) * 8];
            const s16x8 c0 = *(const s16x8*)&WL[(kk * 128 + col0) * 8];
            const s16x8 c1 = *(const s16x8*)&WL[(kk * 128 + col1) * 8];
            acc0 = __builtin_amdgcn_mfma_f32_32x32x16_bf16(ah[kc], b0, acc0, 0, 0, 0);
            acc1 = __builtin_amdgcn_mfma_f32_32x32x16_bf16(ah[kc], b1, acc1, 0, 0, 0);
            acc0 = __builtin_amdgcn_mfma_f32_32x32x16_bf16(al[kc], b0, acc0, 0, 0, 0);
            acc1 = __builtin_amdgcn_mfma_f32_32x32x16_bf16(al[kc], b1, acc1, 0, 0, 0);
            acc0 = __builtin_amdgcn_mfma_f32_32x32x16_bf16(ah[kc], c0, acc0, 0, 0, 0);
            acc1 = __builtin_amdgcn_mfma_f32_32x32x16_bf16(ah[kc], c1, acc1, 0, 0, 0);
        }
        const float* bp = pm ? bs : bq;
        const float b0 = bp[col0], b1 = bp[col1];
        if (pm == 0) {                                  // q -> bf16
            #pragma unroll
            for (int reg = 0; reg < 16; ++reg) {
                const int node = n0 + nt + (reg & 3) + 8 * (reg >> 2) + 4 * g;
                if (node < NN) {
                    unsigned short* qrow = qbf + (size_t)node * 128;
                    qrow[col0] = f2bf(acc0[reg] + b0);
                    qrow[col1] = f2bf(acc1[reg] + b1);
                }
            }
        } else {                                        // skip xs -> fp32
            #pragma unroll
            for (int reg = 0; reg < 16; ++reg) {
                const int node = n0 + nt + (reg & 3) + 8 * (reg >> 2) + 4 * g;
                if (node < NN) {
                    xs[node * 128 + col0] = acc0[reg] + b0;
                    xs[node * 128 + col1] = acc1[reg] + b1;
                }
            }
        }
    }

    // ---- phase K+V interleaved (single hi-term each; 4 loads in flight) ----
    {
        const unsigned short* WK = wHg + 1 * 16384;
        const unsigned short* WV = wHg + 2 * 16384;
        f32x16 ak0, ak1, av0, av1;
        #pragma unroll
        for (int j = 0; j < 16; ++j) { ak0[j] = 0.f; ak1[j] = 0.f; av0[j] = 0.f; av1[j] = 0.f; }
        #pragma unroll
        for (int kc = 0; kc < 8; ++kc) {
            const int kk = (kc << 1) | g;
            const s16x8 k0 = *(const s16x8*)&WK[(kk * 128 + col0) * 8];
            const s16x8 k1 = *(const s16x8*)&WK[(kk * 128 + col1) * 8];
            const s16x8 v0 = *(const s16x8*)&WV[(kk * 128 + col0) * 8];
            const s16x8 v1 = *(const s16x8*)&WV[(kk * 128 + col1) * 8];
            ak0 = __builtin_amdgcn_mfma_f32_32x32x16_bf16(ah[kc], k0, ak0, 0, 0, 0);
            ak1 = __builtin_amdgcn_mfma_f32_32x32x16_bf16(ah[kc], k1, ak1, 0, 0, 0);
            av0 = __builtin_amdgcn_mfma_f32_32x32x16_bf16(ah[kc], v0, av0, 0, 0, 0);
            av1 = __builtin_amdgcn_mfma_f32_32x32x16_bf16(ah[kc], v1, av1, 0, 0, 0);
        }
        const float bk0 = bk[col0], bk1 = bk[col1];
        const float bv0 = bv[col0], bv1 = bv[col1];
        // kv layout (ushorts): kvb[node*256 + h*32 + 0..15]=k, +16..31=v
        const int k0o = (col0 >> 4) * 32 + (col0 & 15);
        const int k1o = (col1 >> 4) * 32 + (col1 & 15);
        #pragma unroll
        for (int reg = 0; reg < 16; ++reg) {
            const int node = n0 + nt + (reg & 3) + 8 * (reg >> 2) + 4 * g;
            if (node < NN) {
                unsigned short* row = kvb + (size_t)node * 256;
                row[k0o]      = f2bf(ak0[reg] + bk0);
                row[k1o]      = f2bf(ak1[reg] + bk1);
                row[k0o + 16] = f2bf(av0[reg] + bv0);
                row[k1o + 16] = f2bf(av1[reg] + bv1);
            }
        }
    }
}

// ---------------------------------------------------------------- attention (CSR, online softmax)
// 32 threads/node, 4-way edge split over SRC-SORTED lists (r18: resident
// blocks sweep src space together -> kv gathers become cache-resident),
// prefetch depth 2, dot2 QK (r17), two-round shfl merge, bf16 q.
__global__ __launch_bounds__(256)
void attn_kernel(const unsigned short* __restrict__ qbf, const uint4* __restrict__ kv4,
                 float* __restrict__ xio,
                 const int* __restrict__ offs, const int* __restrict__ cnts,
                 const int* __restrict__ csrc) {
    const int t = threadIdx.x;
    const int h = t & 7;
    const int quarter = (t >> 3) & 3;
    const int n = blockIdx.x * 8 + (t >> 5);
    const uint4* qp = (const uint4*)(qbf + (size_t)n * 128) + h * 2;
    const uint4 qA = qp[0], qB = qp[1];              // 16 bf16, packed
    float m = -__builtin_inff();
    float d = 0.f;
    float4 a0 = {}, a1 = {}, a2 = {}, a3 = {};
    const int e0 = offs[n], e1 = e0 + cnts[n];
    const int estart = e0 + quarter;
    if (estart < e1) {
        uint4 ka, kb, va, vb;                       // current
        { const uint4* p = kv4 + (size_t)csrc[estart] * 32 + h * 4;
          ka = p[0]; kb = p[1]; va = p[2]; vb = p[3]; }
        uint4 na, nb, nc, nd;                       // next
        if (estart + 4 < e1) {
            const uint4* p = kv4 + (size_t)csrc[estart + 4] * 32 + h * 4;
            na = p[0]; nb = p[1]; nc = p[2]; nd = p[3];
        }
        for (int ec = estart; ec < e1; ec += 4) {
            uint4 fa, fb, fc, fd;                   // next-next
            if (ec + 8 < e1) {
                const uint4* p = kv4 + (size_t)csrc[ec + 8] * 32 + h * 4;
                fa = p[0]; fb = p[1]; fc = p[2]; fd = p[3];
            }
            float dot = 0.f;
            dot = dot2bf(qA.x, ka.x, dot);
            dot = dot2bf(qA.y, ka.y, dot);
            dot = dot2bf(qA.z, ka.z, dot);
            dot = dot2bf(qA.w, ka.w, dot);
            dot = dot2bf(qB.x, kb.x, dot);
            dot = dot2bf(qB.y, kb.y, dot);
            dot = dot2bf(qB.z, kb.z, dot);
            dot = dot2bf(qB.w, kb.w, dot);
            const float alpha = dot * 0.25f;        // / sqrt(C=16)
            const float nm = fmaxf(m, alpha);
            const float scale = __expf(m - nm);     // 0 on first edge
            const float p = __expf(alpha - nm);
            d = d * scale + p;
            a0.x = a0.x * scale + p * B2F_LO(va.x); a0.y = a0.y * scale + p * B2F_HI(va.x);
            a0.z = a0.z * scale + p * B2F_LO(va.y); a0.w = a0.w * scale + p * B2F_HI(va.y);
            a1.x = a1.x * scale + p * B2F_LO(va.z); a1.y = a1.y * scale + p * B2F_HI(va.z);
            a1.z = a1.z * scale + p * B2F_LO(va.w); a1.w = a1.w * scale + p * B2F_HI(va.w);
            a2.x = a2.x * scale + p * B2F_LO(vb.x); a2.y = a2.y * scale + p * B2F_HI(vb.x);
            a2.z = a2.z * scale + p * B2F_LO(vb.y); a2.w = a2.w * scale + p * B2F_HI(vb.y);
            a3.x = a3.x * scale + p * B2F_LO(vb.z); a3.y = a3.y * scale + p * B2F_HI(vb.z);
            a3.z = a3.z * scale + p * B2F_LO(vb.w); a3.w = a3.w * scale + p * B2F_HI(vb.w);
            m = nm;
            ka = na; kb = nb; va = nc; vb = nd;     // shift pipeline
            na = fa; nb = fb; nc = fc; nd = fd;
        }
    }
    // ---- merge the four quarter-streams (exact in fp32): xor 8, then 16 ----
    #pragma unroll
    for (int o = 8; o <= 16; o <<= 1) {
        const float mp = __shfl_xor(m, o);
        const float dp = __shfl_xor(d, o);
        const float mc = fmaxf(fmaxf(m, mp), -1e30f);  // -1e30 guard: empty-stream NaN
        const float s0 = __expf(m - mc);
        const float s1 = __expf(mp - mc);
        d = d * s0 + dp * s1;
        float pa;
        pa = __shfl_xor(a0.x, o); a0.x = a0.x * s0 + pa * s1;
        pa = __shfl_xor(a0.y, o); a0.y = a0.y * s0 + pa * s1;
        pa = __shfl_xor(a0.z, o); a0.z = a0.z * s0 + pa * s1;
        pa = __shfl_xor(a0.w, o); a0.w = a0.w * s0 + pa * s1;
        pa = __shfl_xor(a1.x, o); a1.x = a1.x * s0 + pa * s1;
        pa = __shfl_xor(a1.y, o); a1.y = a1.y * s0 + pa * s1;
        pa = __shfl_xor(a1.z, o); a1.z = a1.z * s0 + pa * s1;
        pa = __shfl_xor(a1.w, o); a1.w = a1.w * s0 + pa * s1;
        pa = __shfl_xor(a2.x, o); a2.x = a2.x * s0 + pa * s1;
        pa = __shfl_xor(a2.y, o); a2.y = a2.y * s0 + pa * s1;
        pa = __shfl_xor(a2.z, o); a2.z = a2.z * s0 + pa * s1;
        pa = __shfl_xor(a2.w, o); a2.w = a2.w * s0 + pa * s1;
        pa = __shfl_xor(a3.x, o); a3.x = a3.x * s0 + pa * s1;
        pa = __shfl_xor(a3.y, o); a3.y = a3.y * s0 + pa * s1;
        pa = __shfl_xor(a3.z, o); a3.z = a3.z * s0 + pa * s1;
        pa = __shfl_xor(a3.w, o); a3.w = a3.w * s0 + pa * s1;
        m = mc;
    }
    if (quarter == 0) {
        const float inv = 1.f / (d + 1e-16f);
        float4* op = (float4*)(xio + (size_t)n * 128 + h * 16);
        float4 o0 = op[0], o1 = op[1], o2 = op[2], o3 = op[3];
        o0.x += a0.x * inv; o0.y += a0.y * inv; o0.z += a0.z * inv; o0.w += a0.w * inv;
        o1.x += a1.x * inv; o1.y += a1.y * inv; o1.z += a1.z * inv; o1.w += a1.w * inv;
        o2.x += a2.x * inv; o2.y += a2.y * inv; o2.z += a2.z * inv; o2.w += a2.w * inv;
        o3.x += a3.x * inv; o3.y += a3.y * inv; o3.z += a3.z * inv; o3.w += a3.w * inv;
        op[0] = o0; op[1] = o1; op[2] = o2; op[3] = o3;
    }
}

// ---------------------------------------------------------------- readout (2-phase, fused gate)
__global__ __launch_bounds__(128)
void pool_partial(const float* __restrict__ x, const float* __restrict__ wg,
                  const float* __restrict__ bg, const int* __restrict__ starts,
                  float* __restrict__ psum, float* __restrict__ pmax) {
    const int g  = blockIdx.x / PCH;
    const int ch = blockIdx.x % PCH;
    const int c  = threadIdx.x;
    const int s0 = starts[g], s1 = starts[g + 1];
    const int total = s1 - s0;
    const int len = (total + PCH - 1) / PCH;
    const int n0 = s0 + ch * len;
    const int n1 = min(n0 + len, s1);
    const float w = wg[c];
    const float b = bg[0];
    __shared__ float red[2];
    float sum = 0.f, mx = -__builtin_inff();
    for (int n = n0; n < n1; ++n) {
        const float xv = x[n * 128 + c];
        float p = xv * w;
        #pragma unroll
        for (int o = 32; o; o >>= 1) p += __shfl_xor(p, o);
        if ((c & 63) == 0) red[c >> 6] = p;
        __syncthreads();
        const float dot = red[0] + red[1];
        __syncthreads();
        const float score = 1.f / (1.f + __expf(-(dot + b)));
        sum += score * xv;
        mx = fmaxf(mx, xv);
    }
    psum[blockIdx.x * 128 + c] = sum;
    pmax[blockIdx.x * 128 + c] = mx;
}

__global__ __launch_bounds__(128)
void pool_final(const float* __restrict__ psum, const float* __restrict__ pmax,
                float* __restrict__ out) {
    const int g = blockIdx.x, c = threadIdx.x;
    float s = 0.f, m = -__builtin_inff();
    #pragma unroll
    for (int ch = 0; ch < PCH; ++ch) {
        s += psum[(g * PCH + ch) * 128 + c];
        m = fmaxf(m, pmax[(g * PCH + ch) * 128 + c]);
    }
    out[g * 256 + c] = s;
    out[g * 256 + 128 + c] = m;
}

// ---------------------------------------------------------------- launch
extern "C" void kernel_launch(void* const* d_in, const int* in_sizes, int n_in,
                              void* d_out, int out_size, void* d_ws, size_t ws_size,
                              hipStream_t stream) {
    const float* x     = (const float*)d_in[0];
    const int*   ei    = (const int*)d_in[1];
    const int*   batch = (const int*)d_in[2];
    const float* Wq = (const float*)d_in[3];
    const float* bq = (const float*)d_in[4];
    const float* Wk = (const float*)d_in[5];
    const float* bk = (const float*)d_in[6];
    const float* Wv = (const float*)d_in[7];
    const float* bv = (const float*)d_in[8];
    const float* Ws = (const float*)d_in[9];
    const float* bs = (const float*)d_in[10];
    const float* wg = (const float*)d_in[11];
    const float* bg = (const float*)d_in[12];
    float* out = (float*)d_out;

    char* w = (char*)d_ws;
    unsigned short* qbf  = (unsigned short*)w; w += (size_t)NN * 128 * 2;
    unsigned short* kvb  = (unsigned short*)w; w += (size_t)NN * 256 * 2;
    float* bufA          = (float*)w;          w += (size_t)NN * 128 * 4;
    float* bufB          = (float*)w;          w += (size_t)NN * 128 * 4;
    float* psum          = (float*)w;          w += (size_t)GG * PCH * 128 * 4;
    float* pmax          = (float*)w;          w += (size_t)GG * PCH * 128 * 4;
    unsigned short* wfh  = (unsigned short*)w; w += (size_t)12 * 16384 * 2;
    unsigned short* wfl  = (unsigned short*)w; w += (size_t)12 * 16384 * 2;
    // zero-region: counts | cursor | gcur  (one memset)
    int* counts          = (int*)w;            w += (size_t)NN * 4;
    int* cursor          = (int*)w;            w += (size_t)NN * 4;
    int* gcur            = (int*)w;            w += (size_t)64 * 4;
    const size_t zero_bytes = (size_t)(NN + NN + 64) * 4;
    int* offsets         = (int*)w;            w += (size_t)NN * 4;
    int* csrc            = (int*)w;            w += (size_t)EE * 4;
    int* starts          = (int*)w;            w += (size_t)(GG + 1) * 4;

    const int* srcI = ei;
    const int* dstI = ei + EE;

    // CSR + edge sort + weight prep
    hipMemsetAsync(counts, 0, zero_bytes, stream);
    hist_kernel<<<(EE + 255) / 256, 256, 0, stream>>>(dstI, counts);
    node_prep<<<SCB, 256, 0, stream>>>(counts, offsets, gcur, batch, starts);
    scatter_kernel<<<(EE + 255) / 256, 256, 0, stream>>>(srcI, dstI, offsets, cursor, csrc);
    sort_edges<<<SCB, 256, 0, stream>>>(offsets, counts, csrc);
    prep_weights<<<dim3(12, 8), 256, 0, stream>>>(Wq, Wk, Wv, Ws, wfh, wfl);

    const float* xin = x;
    float* bufs[2] = {bufA, bufB};
    const int gemmBlocks = (NN + 63) / 64;   // 782
    const int attnBlocks = NN / 8;           // 6250, exact
    for (int l = 0; l < 3; ++l) {
        float* xs = bufs[l & 1];
        gemm_mfma<<<gemmBlocks, 256, 0, stream>>>(
            xin, wfh + (size_t)l * 4 * 16384, wfl + (size_t)l * 4 * 16384,
            bq + (size_t)l * 128, bk + (size_t)l * 128,
            bv + (size_t)l * 128, bs + (size_t)l * 128,
            qbf, kvb, xs);
        attn_kernel<<<attnBlocks, 256, 0, stream>>>(qbf, (const uint4*)kvb, xs, offsets, counts, csrc);
        xin = xs;
    }

    pool_partial<<<GG * PCH, 128, 0, stream>>>(xin, wg, bg, starts, psum, pmax);
    pool_final<<<GG, 128, 0, stream>>>(psum, pmax, out);
}

// Round 19
// 444.590 us; speedup vs baseline: 1.1584x; 1.1584x over previous
//
#include <hip/hip_runtime.h>
#include <hip/hip_bf16.h>

#define NN 50000
#define EE 800000
#define GG 64
#define PCH 16   // pooling chunks per graph
#define SCB ((NN + 255) / 256)   // 196 node blocks
// D=128, H=8, C=16, L=3

typedef __attribute__((ext_vector_type(8)))  short          s16x8;
typedef __attribute__((ext_vector_type(8)))  unsigned short u16x8;
typedef __attribute__((ext_vector_type(16))) float          f32x16;

// bf16 helpers (bit-pattern based)
union BFU { __hip_bfloat16 h; unsigned short u; };
__device__ __forceinline__ unsigned short f2bf(float f) {
    BFU b; b.h = __float2bfloat16(f); return b.u;
}
#define B2F_LO(u) __uint_as_float((u) << 16)
#define B2F_HI(u) __uint_as_float((u) & 0xffff0000u)
#define BF2F(us)  __uint_as_float(((unsigned)(us)) << 16)

// packed 2xbf16 dot with f32 accumulate: D = a.lo*b.lo + a.hi*b.hi + c
__device__ __forceinline__ float dot2bf(unsigned a, unsigned b, float c) {
    float r;
    asm("v_dot2_f32_bf16 %0, %1, %2, %3" : "=v"(r) : "v"(a), "v"(b), "v"(c));
    return r;
}

// ---------------------------------------------------------------- CSR build
__global__ __launch_bounds__(256) void hist_kernel(const int* __restrict__ dst,
                                                   int* __restrict__ counts) {
    int e = blockIdx.x * 256 + threadIdx.x;
    if (e < EE) atomicAdd(&counts[dst[e]], 1);
}

// Single-kernel offsets build: per-block LDS scan + one atomicAdd block-base
// reservation (offsets need not be monotone in node id). Folds in starts.
__global__ __launch_bounds__(256)
void node_prep(const int* __restrict__ counts, int* __restrict__ offsets,
               int* __restrict__ gcur,
               const int* __restrict__ batch, int* __restrict__ starts) {
    __shared__ int sm[256];
    __shared__ int base;
    const int t = threadIdx.x;
    const int i = blockIdx.x * 256 + t;
    const int v = (i < NN) ? counts[i] : 0;
    sm[t] = v;
    __syncthreads();
    for (int off = 1; off < 256; off <<= 1) {
        int val = (t >= off) ? sm[t - off] : 0;
        __syncthreads();
        sm[t] += val;
        __syncthreads();
    }
    if (t == 255) base = atomicAdd(gcur, sm[255]);   // reserve contiguous chunk
    __syncthreads();
    if (i < NN) offsets[i] = base + sm[t] - v;       // exclusive within block
    if (i <= NN) {
        int b  = (i < NN) ? batch[i] : GG;
        int bp = (i == 0) ? -1 : batch[i - 1];
        for (int g = bp + 1; g <= b && g <= GG; ++g) starts[g] = i;
    }
}

__global__ __launch_bounds__(256) void scatter_kernel(const int* __restrict__ src,
                                                      const int* __restrict__ dst,
                                                      const int* __restrict__ offs,
                                                      int* __restrict__ cursor,
                                                      int* __restrict__ csrc) {
    int e = blockIdx.x * 256 + threadIdx.x;
    if (e < EE) {
        int dn = dst[e];
        int p = atomicAdd(&cursor[dn], 1);
        csrc[offs[dn] + p] = src[e];
    }
}

// r19: wave-parallel bitonic sort of each node's edge segment by src id
// (r18's 1-thread/node insertion sort cost 100us at 5% occupancy).
// One 64-lane wave per node, value per lane, 21 shfl_xor compare-exchange
// stages. Sorted lists give resident attn blocks a shared src-window ->
// kv gathers hit L2/L3 (r18: non-sort portion improved 429->415).
__global__ __launch_bounds__(256)
void sort_edges(const int* __restrict__ offs, const int* __restrict__ cnts,
                int* __restrict__ csrc) {
    const int wave = (blockIdx.x * 256 + threadIdx.x) >> 6;
    const int lane = threadIdx.x & 63;
    if (wave >= NN) return;
    const int base = offs[wave], c = cnts[wave];
    if (c <= 1) return;
    if (c <= 64) {
        int v = (lane < c) ? csrc[base + lane] : 0x7fffffff;
        #pragma unroll
        for (int k = 2; k <= 64; k <<= 1) {
            #pragma unroll
            for (int j = k >> 1; j > 0; j >>= 1) {
                const int pv = __shfl_xor(v, j);
                const bool lower = !(lane & j);
                const bool asc   = !(lane & k);   // k=64: ascending everywhere
                const int mn = min(v, pv), mx = max(v, pv);
                v = (lower == asc) ? mn : mx;
            }
        }
        if (lane < c) csrc[base + lane] = v;
    } else if (lane == 0) {                        // unreachable for Poisson(16); safety
        for (int i = 1; i < c; ++i) {
            const int key = csrc[base + i];
            int j = i - 1;
            while (j >= 0 && csrc[base + j] > key) {
                csrc[base + j + 1] = csrc[base + j];
                --j;
            }
            csrc[base + j + 1] = key;
        }
    }
}

// ---------------------------------------------------------------- weight prep
// W[l][k][c] fp32 -> B-FRAGMENT-ORDER split-bf16:
//   wf[mat][(kk*128 + col)*8 + j] = W[kk*8 + j][col],  kk = K-chunk 0..15.
__global__ __launch_bounds__(256)
void prep_weights(const float* __restrict__ Wq, const float* __restrict__ Wk,
                  const float* __restrict__ Wv, const float* __restrict__ Ws,
                  unsigned short* __restrict__ wfh, unsigned short* __restrict__ wfl) {
    const int mat = blockIdx.x;           // 0..11
    const int l = mat >> 2, m = mat & 3;
    const float* W;
    switch (m) {
        case 0:  W = Wq; break;
        case 1:  W = Wk; break;
        case 2:  W = Wv; break;
        default: W = Ws; break;
    }
    W += (size_t)l * 16384;
    const int t = threadIdx.x;
    const int col = blockIdx.y * 16 + (t >> 4);
    const int kk  = t & 15;               // chunk of 8 K values
    u16x8 hi, lo;
    #pragma unroll
    for (int j = 0; j < 8; ++j) {
        float w = W[(kk * 8 + j) * 128 + col];
        unsigned short uh = f2bf(w);
        hi[j] = uh;
        lo[j] = f2bf(w - BF2F(uh));
    }
    const size_t o = (size_t)mat * 16384 + ((size_t)kk * 128 + col) * 8;
    *(u16x8*)(wfh + o) = hi;
    *(u16x8*)(wfl + o) = lo;
}

// ---------------------------------------------------------------- MFMA GEMM
// r15 structure (measured best). 64-node tiles, one barrier, B-frags stream
// from L2 in fragment order. Q (3-term, bf16 out), K+V interleaved (1-term
// each), S (3-term, fp32 out).
__global__ __launch_bounds__(256)
void gemm_mfma(const float* __restrict__ xin,
               const unsigned short* __restrict__ wHg,   // + l*4*16384, frag order
               const unsigned short* __restrict__ wLg,
               const float* __restrict__ bq, const float* __restrict__ bk,
               const float* __restrict__ bv, const float* __restrict__ bs,
               unsigned short* __restrict__ qbf, unsigned short* __restrict__ kvb,
               float* __restrict__ xs) {
    __shared__ unsigned short xl[16384];   // [0..8191]=hi, [8192..]=lo
    const int t = threadIdx.x;
    const int n0 = blockIdx.x * 64;

    // ---- stage x (fp32 -> split bf16, swizzled) ----
    const float4* X4 = (const float4*)xin;
    for (int i = t; i < 1024; i += 256) {            // 64 rows x 16 chunks
        const int row = i >> 4, ch = i & 15;
        const int node = n0 + row;
        float4 fa = make_float4(0.f, 0.f, 0.f, 0.f);
        float4 fb = make_float4(0.f, 0.f, 0.f, 0.f);
        if (node < NN) { fa = X4[node * 32 + ch * 2]; fb = X4[node * 32 + ch * 2 + 1]; }
        const float fv[8] = {fa.x, fa.y, fa.z, fa.w, fb.x, fb.y, fb.z, fb.w};
        u16x8 hi, lo;
        #pragma unroll
        for (int j = 0; j < 8; ++j) {
            unsigned short uh = f2bf(fv[j]);
            hi[j] = uh;
            lo[j] = f2bf(fv[j] - BF2F(uh));
        }
        const int base = row * 128 + (ch ^ (row & 7)) * 8;
        *(u16x8*)&xl[base] = hi;
        *(u16x8*)&xl[8192 + base] = lo;
    }
    __syncthreads();

    // ---- per-wave tile & A-fragments ----
    const int lane = t & 63, wid = t >> 6;
    const int r = lane & 31, g = lane >> 5;
    const int nt = (wid & 1) * 32;        // node offset in tile
    const int cb = (wid >> 1) * 64;       // col base
    s16x8 ah[8], al[8];
    {
        const int row = nt + r;
        const int s = row & 7;
        const int rb = row * 128;
        #pragma unroll
        for (int kc = 0; kc < 8; ++kc) {
            const int idx = rb + (((kc << 1) | g) ^ s) * 8;
            ah[kc] = *(const s16x8*)&xl[idx];
            al[kc] = *(const s16x8*)&xl[8192 + idx];
        }
    }
    const int col0 = cb + r, col1 = cb + 32 + r;

    // ---- phase Q (bf16 out) and phase S (fp32 out), 3-term split-bf16 ----
    #pragma unroll
    for (int pm = 0; pm < 2; ++pm) {
        const int m = pm ? 3 : 0;
        const unsigned short* WH = wHg + m * 16384;
        const unsigned short* WL = wLg + m * 16384;
        f32x16 acc0, acc1;
        #pragma unroll
        for (int j = 0; j < 16; ++j) { acc0[j] = 0.f; acc1[j] = 0.f; }
        #pragma unroll
        for (int kc = 0; kc < 8; ++kc) {
            const int kk = (kc << 1) | g;
            const s16x8 b0 = *(const s16x8*)&WH[(kk * 128 + col0) * 8];
            const s16x8 b1 = *(const s16x8*)&WH[(kk * 128 + col1) * 8];
            const s16x8 c0 = *(const s16x8*)&WL[(kk * 128 + col0) * 8];
            const s16x8 c1 = *(const s16x8*)&WL[(kk * 128 + col1) * 8];
            acc0 = __builtin_amdgcn_mfma_f32_32x32x16_bf16(ah[kc], b0, acc0, 0, 0, 0);
            acc1 = __builtin_amdgcn_mfma_f32_32x32x16_bf16(ah[kc], b1, acc1, 0, 0, 0);
            acc0 = __builtin_amdgcn_mfma_f32_32x32x16_bf16(al[kc], b0, acc0, 0, 0, 0);
            acc1 = __builtin_amdgcn_mfma_f32_32x32x16_bf16(al[kc], b1, acc1, 0, 0, 0);
            acc0 = __builtin_amdgcn_mfma_f32_32x32x16_bf16(ah[kc], c0, acc0, 0, 0, 0);
            acc1 = __builtin_amdgcn_mfma_f32_32x32x16_bf16(ah[kc], c1, acc1, 0, 0, 0);
        }
        const float* bp = pm ? bs : bq;
        const float b0 = bp[col0], b1 = bp[col1];
        if (pm == 0) {                                  // q -> bf16
            #pragma unroll
            for (int reg = 0; reg < 16; ++reg) {
                const int node = n0 + nt + (reg & 3) + 8 * (reg >> 2) + 4 * g;
                if (node < NN) {
                    unsigned short* qrow = qbf + (size_t)node * 128;
                    qrow[col0] = f2bf(acc0[reg] + b0);
                    qrow[col1] = f2bf(acc1[reg] + b1);
                }
            }
        } else {                                        // skip xs -> fp32
            #pragma unroll
            for (int reg = 0; reg < 16; ++reg) {
                const int node = n0 + nt + (reg & 3) + 8 * (reg >> 2) + 4 * g;
                if (node < NN) {
                    xs[node * 128 + col0] = acc0[reg] + b0;
                    xs[node * 128 + col1] = acc1[reg] + b1;
                }
            }
        }
    }

    // ---- phase K+V interleaved (single hi-term each; 4 loads in flight) ----
    {
        const unsigned short* WK = wHg + 1 * 16384;
        const unsigned short* WV = wHg + 2 * 16384;
        f32x16 ak0, ak1, av0, av1;
        #pragma unroll
        for (int j = 0; j < 16; ++j) { ak0[j] = 0.f; ak1[j] = 0.f; av0[j] = 0.f; av1[j] = 0.f; }
        #pragma unroll
        for (int kc = 0; kc < 8; ++kc) {
            const int kk = (kc << 1) | g;
            const s16x8 k0 = *(const s16x8*)&WK[(kk * 128 + col0) * 8];
            const s16x8 k1 = *(const s16x8*)&WK[(kk * 128 + col1) * 8];
            const s16x8 v0 = *(const s16x8*)&WV[(kk * 128 + col0) * 8];
            const s16x8 v1 = *(const s16x8*)&WV[(kk * 128 + col1) * 8];
            ak0 = __builtin_amdgcn_mfma_f32_32x32x16_bf16(ah[kc], k0, ak0, 0, 0, 0);
            ak1 = __builtin_amdgcn_mfma_f32_32x32x16_bf16(ah[kc], k1, ak1, 0, 0, 0);
            av0 = __builtin_amdgcn_mfma_f32_32x32x16_bf16(ah[kc], v0, av0, 0, 0, 0);
            av1 = __builtin_amdgcn_mfma_f32_32x32x16_bf16(ah[kc], v1, av1, 0, 0, 0);
        }
        const float bk0 = bk[col0], bk1 = bk[col1];
        const float bv0 = bv[col0], bv1 = bv[col1];
        // kv layout (ushorts): kvb[node*256 + h*32 + 0..15]=k, +16..31=v
        const int k0o = (col0 >> 4) * 32 + (col0 & 15);
        const int k1o = (col1 >> 4) * 32 + (col1 & 15);
        #pragma unroll
        for (int reg = 0; reg < 16; ++reg) {
            const int node = n0 + nt + (reg & 3) + 8 * (reg >> 2) + 4 * g;
            if (node < NN) {
                unsigned short* row = kvb + (size_t)node * 256;
                row[k0o]      = f2bf(ak0[reg] + bk0);
                row[k1o]      = f2bf(ak1[reg] + bk1);
                row[k0o + 16] = f2bf(av0[reg] + bv0);
                row[k1o + 16] = f2bf(av1[reg] + bv1);
            }
        }
    }
}

// ---------------------------------------------------------------- attention (CSR, online softmax)
// 32 threads/node, 4-way edge split over SRC-SORTED lists, prefetch depth 2,
// dot2 QK, two-round shfl merge, bf16 q.
__global__ __launch_bounds__(256)
void attn_kernel(const unsigned short* __restrict__ qbf, const uint4* __restrict__ kv4,
                 float* __restrict__ xio,
                 const int* __restrict__ offs, const int* __restrict__ cnts,
                 const int* __restrict__ csrc) {
    const int t = threadIdx.x;
    const int h = t & 7;
    const int quarter = (t >> 3) & 3;
    const int n = blockIdx.x * 8 + (t >> 5);
    const uint4* qp = (const uint4*)(qbf + (size_t)n * 128) + h * 2;
    const uint4 qA = qp[0], qB = qp[1];              // 16 bf16, packed
    float m = -__builtin_inff();
    float d = 0.f;
    float4 a0 = {}, a1 = {}, a2 = {}, a3 = {};
    const int e0 = offs[n], e1 = e0 + cnts[n];
    const int estart = e0 + quarter;
    if (estart < e1) {
        uint4 ka, kb, va, vb;                       // current
        { const uint4* p = kv4 + (size_t)csrc[estart] * 32 + h * 4;
          ka = p[0]; kb = p[1]; va = p[2]; vb = p[3]; }
        uint4 na, nb, nc, nd;                       // next
        if (estart + 4 < e1) {
            const uint4* p = kv4 + (size_t)csrc[estart + 4] * 32 + h * 4;
            na = p[0]; nb = p[1]; nc = p[2]; nd = p[3];
        }
        for (int ec = estart; ec < e1; ec += 4) {
            uint4 fa, fb, fc, fd;                   // next-next
            if (ec + 8 < e1) {
                const uint4* p = kv4 + (size_t)csrc[ec + 8] * 32 + h * 4;
                fa = p[0]; fb = p[1]; fc = p[2]; fd = p[3];
            }
            float dot = 0.f;
            dot = dot2bf(qA.x, ka.x, dot);
            dot = dot2bf(qA.y, ka.y, dot);
            dot = dot2bf(qA.z, ka.z, dot);
            dot = dot2bf(qA.w, ka.w, dot);
            dot = dot2bf(qB.x, kb.x, dot);
            dot = dot2bf(qB.y, kb.y, dot);
            dot = dot2bf(qB.z, kb.z, dot);
            dot = dot2bf(qB.w, kb.w, dot);
            const float alpha = dot * 0.25f;        // / sqrt(C=16)
            const float nm = fmaxf(m, alpha);
            const float scale = __expf(m - nm);     // 0 on first edge
            const float p = __expf(alpha - nm);
            d = d * scale + p;
            a0.x = a0.x * scale + p * B2F_LO(va.x); a0.y = a0.y * scale + p * B2F_HI(va.x);
            a0.z = a0.z * scale + p * B2F_LO(va.y); a0.w = a0.w * scale + p * B2F_HI(va.y);
            a1.x = a1.x * scale + p * B2F_LO(va.z); a1.y = a1.y * scale + p * B2F_HI(va.z);
            a1.z = a1.z * scale + p * B2F_LO(va.w); a1.w = a1.w * scale + p * B2F_HI(va.w);
            a2.x = a2.x * scale + p * B2F_LO(vb.x); a2.y = a2.y * scale + p * B2F_HI(vb.x);
            a2.z = a2.z * scale + p * B2F_LO(vb.y); a2.w = a2.w * scale + p * B2F_HI(vb.y);
            a3.x = a3.x * scale + p * B2F_LO(vb.z); a3.y = a3.y * scale + p * B2F_HI(vb.z);
            a3.z = a3.z * scale + p * B2F_LO(vb.w); a3.w = a3.w * scale + p * B2F_HI(vb.w);
            m = nm;
            ka = na; kb = nb; va = nc; vb = nd;     // shift pipeline
            na = fa; nb = fb; nc = fc; nd = fd;
        }
    }
    // ---- merge the four quarter-streams (exact in fp32): xor 8, then 16 ----
    #pragma unroll
    for (int o = 8; o <= 16; o <<= 1) {
        const float mp = __shfl_xor(m, o);
        const float dp = __shfl_xor(d, o);
        const float mc = fmaxf(fmaxf(m, mp), -1e30f);  // -1e30 guard: empty-stream NaN
        const float s0 = __expf(m - mc);
        const float s1 = __expf(mp - mc);
        d = d * s0 + dp * s1;
        float pa;
        pa = __shfl_xor(a0.x, o); a0.x = a0.x * s0 + pa * s1;
        pa = __shfl_xor(a0.y, o); a0.y = a0.y * s0 + pa * s1;
        pa = __shfl_xor(a0.z, o); a0.z = a0.z * s0 + pa * s1;
        pa = __shfl_xor(a0.w, o); a0.w = a0.w * s0 + pa * s1;
        pa = __shfl_xor(a1.x, o); a1.x = a1.x * s0 + pa * s1;
        pa = __shfl_xor(a1.y, o); a1.y = a1.y * s0 + pa * s1;
        pa = __shfl_xor(a1.z, o); a1.z = a1.z * s0 + pa * s1;
        pa = __shfl_xor(a1.w, o); a1.w = a1.w * s0 + pa * s1;
        pa = __shfl_xor(a2.x, o); a2.x = a2.x * s0 + pa * s1;
        pa = __shfl_xor(a2.y, o); a2.y = a2.y * s0 + pa * s1;
        pa = __shfl_xor(a2.z, o); a2.z = a2.z * s0 + pa * s1;
        pa = __shfl_xor(a2.w, o); a2.w = a2.w * s0 + pa * s1;
        pa = __shfl_xor(a3.x, o); a3.x = a3.x * s0 + pa * s1;
        pa = __shfl_xor(a3.y, o); a3.y = a3.y * s0 + pa * s1;
        pa = __shfl_xor(a3.z, o); a3.z = a3.z * s0 + pa * s1;
        pa = __shfl_xor(a3.w, o); a3.w = a3.w * s0 + pa * s1;
        m = mc;
    }
    if (quarter == 0) {
        const float inv = 1.f / (d + 1e-16f);
        float4* op = (float4*)(xio + (size_t)n * 128 + h * 16);
        float4 o0 = op[0], o1 = op[1], o2 = op[2], o3 = op[3];
        o0.x += a0.x * inv; o0.y += a0.y * inv; o0.z += a0.z * inv; o0.w += a0.w * inv;
        o1.x += a1.x * inv; o1.y += a1.y * inv; o1.z += a1.z * inv; o1.w += a1.w * inv;
        o2.x += a2.x * inv; o2.y += a2.y * inv; o2.z += a2.z * inv; o2.w += a2.w * inv;
        o3.x += a3.x * inv; o3.y += a3.y * inv; o3.z += a3.z * inv; o3.w += a3.w * inv;
        op[0] = o0; op[1] = o1; op[2] = o2; op[3] = o3;
    }
}

// ---------------------------------------------------------------- readout (2-phase, fused gate)
__global__ __launch_bounds__(128)
void pool_partial(const float* __restrict__ x, const float* __restrict__ wg,
                  const float* __restrict__ bg, const int* __restrict__ starts,
                  float* __restrict__ psum, float* __restrict__ pmax) {
    const int g  = blockIdx.x / PCH;
    const int ch = blockIdx.x % PCH;
    const int c  = threadIdx.x;
    const int s0 = starts[g], s1 = starts[g + 1];
    const int total = s1 - s0;
    const int len = (total + PCH - 1) / PCH;
    const int n0 = s0 + ch * len;
    const int n1 = min(n0 + len, s1);
    const float w = wg[c];
    const float b = bg[0];
    __shared__ float red[2];
    float sum = 0.f, mx = -__builtin_inff();
    for (int n = n0; n < n1; ++n) {
        const float xv = x[n * 128 + c];
        float p = xv * w;
        #pragma unroll
        for (int o = 32; o; o >>= 1) p += __shfl_xor(p, o);
        if ((c & 63) == 0) red[c >> 6] = p;
        __syncthreads();
        const float dot = red[0] + red[1];
        __syncthreads();
        const float score = 1.f / (1.f + __expf(-(dot + b)));
        sum += score * xv;
        mx = fmaxf(mx, xv);
    }
    psum[blockIdx.x * 128 + c] = sum;
    pmax[blockIdx.x * 128 + c] = mx;
}

__global__ __launch_bounds__(128)
void pool_final(const float* __restrict__ psum, const float* __restrict__ pmax,
                float* __restrict__ out) {
    const int g = blockIdx.x, c = threadIdx.x;
    float s = 0.f, m = -__builtin_inff();
    #pragma unroll
    for (int ch = 0; ch < PCH; ++ch) {
        s += psum[(g * PCH + ch) * 128 + c];
        m = fmaxf(m, pmax[(g * PCH + ch) * 128 + c]);
    }
    out[g * 256 + c] = s;
    out[g * 256 + 128 + c] = m;
}

// ---------------------------------------------------------------- launch
extern "C" void kernel_launch(void* const* d_in, const int* in_sizes, int n_in,
                              void* d_out, int out_size, void* d_ws, size_t ws_size,
                              hipStream_t stream) {
    const float* x     = (const float*)d_in[0];
    const int*   ei    = (const int*)d_in[1];
    const int*   batch = (const int*)d_in[2];
    const float* Wq = (const float*)d_in[3];
    const float* bq = (const float*)d_in[4];
    const float* Wk = (const float*)d_in[5];
    const float* bk = (const float*)d_in[6];
    const float* Wv = (const float*)d_in[7];
    const float* bv = (const float*)d_in[8];
    const float* Ws = (const float*)d_in[9];
    const float* bs = (const float*)d_in[10];
    const float* wg = (const float*)d_in[11];
    const float* bg = (const float*)d_in[12];
    float* out = (float*)d_out;

    char* w = (char*)d_ws;
    unsigned short* qbf  = (unsigned short*)w; w += (size_t)NN * 128 * 2;
    unsigned short* kvb  = (unsigned short*)w; w += (size_t)NN * 256 * 2;
    float* bufA          = (float*)w;          w += (size_t)NN * 128 * 4;
    float* bufB          = (float*)w;          w += (size_t)NN * 128 * 4;
    float* psum          = (float*)w;          w += (size_t)GG * PCH * 128 * 4;
    float* pmax          = (float*)w;          w += (size_t)GG * PCH * 128 * 4;
    unsigned short* wfh  = (unsigned short*)w; w += (size_t)12 * 16384 * 2;
    unsigned short* wfl  = (unsigned short*)w; w += (size_t)12 * 16384 * 2;
    // zero-region: counts | cursor | gcur  (one memset)
    int* counts          = (int*)w;            w += (size_t)NN * 4;
    int* cursor          = (int*)w;            w += (size_t)NN * 4;
    int* gcur            = (int*)w;            w += (size_t)64 * 4;
    const size_t zero_bytes = (size_t)(NN + NN + 64) * 4;
    int* offsets         = (int*)w;            w += (size_t)NN * 4;
    int* csrc            = (int*)w;            w += (size_t)EE * 4;
    int* starts          = (int*)w;            w += (size_t)(GG + 1) * 4;

    const int* srcI = ei;
    const int* dstI = ei + EE;

    // CSR + edge sort + weight prep
    hipMemsetAsync(counts, 0, zero_bytes, stream);
    hist_kernel<<<(EE + 255) / 256, 256, 0, stream>>>(dstI, counts);
    node_prep<<<SCB, 256, 0, stream>>>(counts, offsets, gcur, batch, starts);
    scatter_kernel<<<(EE + 255) / 256, 256, 0, stream>>>(srcI, dstI, offsets, cursor, csrc);
    sort_edges<<<(NN * 64 + 255) / 256, 256, 0, stream>>>(offsets, counts, csrc);
    prep_weights<<<dim3(12, 8), 256, 0, stream>>>(Wq, Wk, Wv, Ws, wfh, wfl);

    const float* xin = x;
    float* bufs[2] = {bufA, bufB};
    const int gemmBlocks = (NN + 63) / 64;   // 782
    const int attnBlocks = NN / 8;           // 6250, exact
    for (int l = 0; l < 3; ++l) {
        float* xs = bufs[l & 1];
        gemm_mfma<<<gemmBlocks, 256, 0, stream>>>(
            xin, wfh + (size_t)l * 4 * 16384, wfl + (size_t)l * 4 * 16384,
            bq + (size_t)l * 128, bk + (size_t)l * 128,
            bv + (size_t)l * 128, bs + (size_t)l * 128,
            qbf, kvb, xs);
        attn_kernel<<<attnBlocks, 256, 0, stream>>>(qbf, (const uint4*)kvb, xs, offsets, counts, csrc);
        xin = xs;
    }

    pool_partial<<<GG * PCH, 128, 0, stream>>>(xin, wg, bg, starts, psum, pmax);
    pool_final<<<GG, 128, 0, stream>>>(psum, pmax, out);
}

// Round 20
// 428.774 us; speedup vs baseline: 1.2011x; 1.0369x over previous
//
#include <hip/hip_runtime.h>
#include <hip/hip_bf16.h>

#define NN 50000
#define EE 800000
#define GG 64
#define PCH 16   // pooling chunks per graph
#define SCB ((NN + 255) / 256)   // 196 node blocks
// D=128, H=8, C=16, L=3

typedef __attribute__((ext_vector_type(8)))  short          s16x8;
typedef __attribute__((ext_vector_type(8)))  unsigned short u16x8;
typedef __attribute__((ext_vector_type(16))) float          f32x16;

// bf16 helpers (bit-pattern based)
union BFU { __hip_bfloat16 h; unsigned short u; };
__device__ __forceinline__ unsigned short f2bf(float f) {
    BFU b; b.h = __float2bfloat16(f); return b.u;
}
#define B2F_LO(u) __uint_as_float((u) << 16)
#define B2F_HI(u) __uint_as_float((u) & 0xffff0000u)
#define BF2F(us)  __uint_as_float(((unsigned)(us)) << 16)

// packed 2xbf16 dot with f32 accumulate: D = a.lo*b.lo + a.hi*b.hi + c
__device__ __forceinline__ float dot2bf(unsigned a, unsigned b, float c) {
    float r;
    asm("v_dot2_f32_bf16 %0, %1, %2, %3" : "=v"(r) : "v"(a), "v"(b), "v"(c));
    return r;
}

// ---------------------------------------------------------------- CSR build
__global__ __launch_bounds__(256) void hist_kernel(const int* __restrict__ dst,
                                                   int* __restrict__ counts) {
    int e = blockIdx.x * 256 + threadIdx.x;
    if (e < EE) atomicAdd(&counts[dst[e]], 1);
}

// Single-kernel offsets build: per-block LDS scan + one atomicAdd block-base
// reservation (offsets need not be monotone in node id). Folds in starts.
__global__ __launch_bounds__(256)
void node_prep(const int* __restrict__ counts, int* __restrict__ offsets,
               int* __restrict__ gcur,
               const int* __restrict__ batch, int* __restrict__ starts) {
    __shared__ int sm[256];
    __shared__ int base;
    const int t = threadIdx.x;
    const int i = blockIdx.x * 256 + t;
    const int v = (i < NN) ? counts[i] : 0;
    sm[t] = v;
    __syncthreads();
    for (int off = 1; off < 256; off <<= 1) {
        int val = (t >= off) ? sm[t - off] : 0;
        __syncthreads();
        sm[t] += val;
        __syncthreads();
    }
    if (t == 255) base = atomicAdd(gcur, sm[255]);   // reserve contiguous chunk
    __syncthreads();
    if (i < NN) offsets[i] = base + sm[t] - v;       // exclusive within block
    if (i <= NN) {
        int b  = (i < NN) ? batch[i] : GG;
        int bp = (i == 0) ? -1 : batch[i - 1];
        for (int g = bp + 1; g <= b && g <= GG; ++g) starts[g] = i;
    }
}

__global__ __launch_bounds__(256) void scatter_kernel(const int* __restrict__ src,
                                                      const int* __restrict__ dst,
                                                      const int* __restrict__ offs,
                                                      int* __restrict__ cursor,
                                                      int* __restrict__ csrc) {
    int e = blockIdx.x * 256 + threadIdx.x;
    if (e < EE) {
        int dn = dst[e];
        int p = atomicAdd(&cursor[dn], 1);
        csrc[offs[dn] + p] = src[e];
    }
}

// ---------------------------------------------------------------- weight prep
// W[l][k][c] fp32 -> B-FRAGMENT-ORDER split-bf16:
//   wf[mat][(kk*128 + col)*8 + j] = W[kk*8 + j][col],  kk = K-chunk 0..15.
__global__ __launch_bounds__(256)
void prep_weights(const float* __restrict__ Wq, const float* __restrict__ Wk,
                  const float* __restrict__ Wv, const float* __restrict__ Ws,
                  unsigned short* __restrict__ wfh, unsigned short* __restrict__ wfl) {
    const int mat = blockIdx.x;           // 0..11
    const int l = mat >> 2, m = mat & 3;
    const float* W;
    switch (m) {
        case 0:  W = Wq; break;
        case 1:  W = Wk; break;
        case 2:  W = Wv; break;
        default: W = Ws; break;
    }
    W += (size_t)l * 16384;
    const int t = threadIdx.x;
    const int col = blockIdx.y * 16 + (t >> 4);
    const int kk  = t & 15;               // chunk of 8 K values
    u16x8 hi, lo;
    #pragma unroll
    for (int j = 0; j < 8; ++j) {
        float w = W[(kk * 8 + j) * 128 + col];
        unsigned short uh = f2bf(w);
        hi[j] = uh;
        lo[j] = f2bf(w - BF2F(uh));
    }
    const size_t o = (size_t)mat * 16384 + ((size_t)kk * 128 + col) * 8;
    *(u16x8*)(wfh + o) = hi;
    *(u16x8*)(wfl + o) = lo;
}

// ---------------------------------------------------------------- MFMA GEMM
// r15/r17 structure (measured best). 64-node tiles, one barrier, B-frags
// stream from L2 in fragment order. Q (3-term split-bf16, bf16 out),
// K+V interleaved (1-term each), S (3-term, fp32 out).
__global__ __launch_bounds__(256)
void gemm_mfma(const float* __restrict__ xin,
               const unsigned short* __restrict__ wHg,   // + l*4*16384, frag order
               const unsigned short* __restrict__ wLg,
               const float* __restrict__ bq, const float* __restrict__ bk,
               const float* __restrict__ bv, const float* __restrict__ bs,
               unsigned short* __restrict__ qbf, unsigned short* __restrict__ kvb,
               float* __restrict__ xs) {
    __shared__ unsigned short xl[16384];   // [0..8191]=hi, [8192..]=lo
    const int t = threadIdx.x;
    const int n0 = blockIdx.x * 64;

    // ---- stage x (fp32 -> split bf16, swizzled) ----
    const float4* X4 = (const float4*)xin;
    for (int i = t; i < 1024; i += 256) {            // 64 rows x 16 chunks
        const int row = i >> 4, ch = i & 15;
        const int node = n0 + row;
        float4 fa = make_float4(0.f, 0.f, 0.f, 0.f);
        float4 fb = make_float4(0.f, 0.f, 0.f, 0.f);
        if (node < NN) { fa = X4[node * 32 + ch * 2]; fb = X4[node * 32 + ch * 2 + 1]; }
        const float fv[8] = {fa.x, fa.y, fa.z, fa.w, fb.x, fb.y, fb.z, fb.w};
        u16x8 hi, lo;
        #pragma unroll
        for (int j = 0; j < 8; ++j) {
            unsigned short uh = f2bf(fv[j]);
            hi[j] = uh;
            lo[j] = f2bf(fv[j] - BF2F(uh));
        }
        const int base = row * 128 + (ch ^ (row & 7)) * 8;
        *(u16x8*)&xl[base] = hi;
        *(u16x8*)&xl[8192 + base] = lo;
    }
    __syncthreads();

    // ---- per-wave tile & A-fragments ----
    const int lane = t & 63, wid = t >> 6;
    const int r = lane & 31, g = lane >> 5;
    const int nt = (wid & 1) * 32;        // node offset in tile
    const int cb = (wid >> 1) * 64;       // col base
    s16x8 ah[8], al[8];
    {
        const int row = nt + r;
        const int s = row & 7;
        const int rb = row * 128;
        #pragma unroll
        for (int kc = 0; kc < 8; ++kc) {
            const int idx = rb + (((kc << 1) | g) ^ s) * 8;
            ah[kc] = *(const s16x8*)&xl[idx];
            al[kc] = *(const s16x8*)&xl[8192 + idx];
        }
    }
    const int col0 = cb + r, col1 = cb + 32 + r;

    // ---- phase Q (bf16 out) and phase S (fp32 out), 3-term split-bf16 ----
    #pragma unroll
    for (int pm = 0; pm < 2; ++pm) {
        const int m = pm ? 3 : 0;
        const unsigned short* WH = wHg + m * 16384;
        const unsigned short* WL = wLg + m * 16384;
        f32x16 acc0, acc1;
        #pragma unroll
        for (int j = 0; j < 16; ++j) { acc0[j] = 0.f; acc1[j] = 0.f; }
        #pragma unroll
        for (int kc = 0; kc < 8; ++kc) {
            const int kk = (kc << 1) | g;
            const s16x8 b0 = *(const s16x8*)&WH[(kk * 128 + col0) * 8];
            const s16x8 b1 = *(const s16x8*)&WH[(kk * 128 + col1) * 8];
            const s16x8 c0 = *(const s16x8*)&WL[(kk * 128 + col0) * 8];
            const s16x8 c1 = *(const s16x8*)&WL[(kk * 128 + col1) * 8];
            acc0 = __builtin_amdgcn_mfma_f32_32x32x16_bf16(ah[kc], b0, acc0, 0, 0, 0);
            acc1 = __builtin_amdgcn_mfma_f32_32x32x16_bf16(ah[kc], b1, acc1, 0, 0, 0);
            acc0 = __builtin_amdgcn_mfma_f32_32x32x16_bf16(al[kc], b0, acc0, 0, 0, 0);
            acc1 = __builtin_amdgcn_mfma_f32_32x32x16_bf16(al[kc], b1, acc1, 0, 0, 0);
            acc0 = __builtin_amdgcn_mfma_f32_32x32x16_bf16(ah[kc], c0, acc0, 0, 0, 0);
            acc1 = __builtin_amdgcn_mfma_f32_32x32x16_bf16(ah[kc], c1, acc1, 0, 0, 0);
        }
        const float* bp = pm ? bs : bq;
        const float b0 = bp[col0], b1 = bp[col1];
        if (pm == 0) {                                  // q -> bf16
            #pragma unroll
            for (int reg = 0; reg < 16; ++reg) {
                const int node = n0 + nt + (reg & 3) + 8 * (reg >> 2) + 4 * g;
                if (node < NN) {
                    unsigned short* qrow = qbf + (size_t)node * 128;
                    qrow[col0] = f2bf(acc0[reg] + b0);
                    qrow[col1] = f2bf(acc1[reg] + b1);
                }
            }
        } else {                                        // skip xs -> fp32
            #pragma unroll
            for (int reg = 0; reg < 16; ++reg) {
                const int node = n0 + nt + (reg & 3) + 8 * (reg >> 2) + 4 * g;
                if (node < NN) {
                    xs[node * 128 + col0] = acc0[reg] + b0;
                    xs[node * 128 + col1] = acc1[reg] + b1;
                }
            }
        }
    }

    // ---- phase K+V interleaved (single hi-term each; 4 loads in flight) ----
    {
        const unsigned short* WK = wHg + 1 * 16384;
        const unsigned short* WV = wHg + 2 * 16384;
        f32x16 ak0, ak1, av0, av1;
        #pragma unroll
        for (int j = 0; j < 16; ++j) { ak0[j] = 0.f; ak1[j] = 0.f; av0[j] = 0.f; av1[j] = 0.f; }
        #pragma unroll
        for (int kc = 0; kc < 8; ++kc) {
            const int kk = (kc << 1) | g;
            const s16x8 k0 = *(const s16x8*)&WK[(kk * 128 + col0) * 8];
            const s16x8 k1 = *(const s16x8*)&WK[(kk * 128 + col1) * 8];
            const s16x8 v0 = *(const s16x8*)&WV[(kk * 128 + col0) * 8];
            const s16x8 v1 = *(const s16x8*)&WV[(kk * 128 + col1) * 8];
            ak0 = __builtin_amdgcn_mfma_f32_32x32x16_bf16(ah[kc], k0, ak0, 0, 0, 0);
            ak1 = __builtin_amdgcn_mfma_f32_32x32x16_bf16(ah[kc], k1, ak1, 0, 0, 0);
            av0 = __builtin_amdgcn_mfma_f32_32x32x16_bf16(ah[kc], v0, av0, 0, 0, 0);
            av1 = __builtin_amdgcn_mfma_f32_32x32x16_bf16(ah[kc], v1, av1, 0, 0, 0);
        }
        const float bk0 = bk[col0], bk1 = bk[col1];
        const float bv0 = bv[col0], bv1 = bv[col1];
        // kv layout (ushorts): kvb[node*256 + h*32 + 0..15]=k, +16..31=v
        const int k0o = (col0 >> 4) * 32 + (col0 & 15);
        const int k1o = (col1 >> 4) * 32 + (col1 & 15);
        #pragma unroll
        for (int reg = 0; reg < 16; ++reg) {
            const int node = n0 + nt + (reg & 3) + 8 * (reg >> 2) + 4 * g;
            if (node < NN) {
                unsigned short* row = kvb + (size_t)node * 256;
                row[k0o]      = f2bf(ak0[reg] + bk0);
                row[k1o]      = f2bf(ak1[reg] + bk1);
                row[k0o + 16] = f2bf(av0[reg] + bv0);
                row[k1o + 16] = f2bf(av1[reg] + bv1);
            }
        }
    }
}

// ---------------------------------------------------------------- attention (CSR, online softmax)
// r17 configuration (measured best). 32 threads/node, 4-way edge split,
// prefetch depth 2, dot2 QK, two-round shfl merge, bf16 q.
// [r18/r19: src-sorting the edge lists measured NULL — dropped.]
__global__ __launch_bounds__(256)
void attn_kernel(const unsigned short* __restrict__ qbf, const uint4* __restrict__ kv4,
                 float* __restrict__ xio,
                 const int* __restrict__ offs, const int* __restrict__ cnts,
                 const int* __restrict__ csrc) {
    const int t = threadIdx.x;
    const int h = t & 7;
    const int quarter = (t >> 3) & 3;
    const int n = blockIdx.x * 8 + (t >> 5);
    const uint4* qp = (const uint4*)(qbf + (size_t)n * 128) + h * 2;
    const uint4 qA = qp[0], qB = qp[1];              // 16 bf16, packed
    float m = -__builtin_inff();
    float d = 0.f;
    float4 a0 = {}, a1 = {}, a2 = {}, a3 = {};
    const int e0 = offs[n], e1 = e0 + cnts[n];
    const int estart = e0 + quarter;
    if (estart < e1) {
        uint4 ka, kb, va, vb;                       // current
        { const uint4* p = kv4 + (size_t)csrc[estart] * 32 + h * 4;
          ka = p[0]; kb = p[1]; va = p[2]; vb = p[3]; }
        uint4 na, nb, nc, nd;                       // next
        if (estart + 4 < e1) {
            const uint4* p = kv4 + (size_t)csrc[estart + 4] * 32 + h * 4;
            na = p[0]; nb = p[1]; nc = p[2]; nd = p[3];
        }
        for (int ec = estart; ec < e1; ec += 4) {
            uint4 fa, fb, fc, fd;                   // next-next
            if (ec + 8 < e1) {
                const uint4* p = kv4 + (size_t)csrc[ec + 8] * 32 + h * 4;
                fa = p[0]; fb = p[1]; fc = p[2]; fd = p[3];
            }
            float dot = 0.f;
            dot = dot2bf(qA.x, ka.x, dot);
            dot = dot2bf(qA.y, ka.y, dot);
            dot = dot2bf(qA.z, ka.z, dot);
            dot = dot2bf(qA.w, ka.w, dot);
            dot = dot2bf(qB.x, kb.x, dot);
            dot = dot2bf(qB.y, kb.y, dot);
            dot = dot2bf(qB.z, kb.z, dot);
            dot = dot2bf(qB.w, kb.w, dot);
            const float alpha = dot * 0.25f;        // / sqrt(C=16)
            const float nm = fmaxf(m, alpha);
            const float scale = __expf(m - nm);     // 0 on first edge
            const float p = __expf(alpha - nm);
            d = d * scale + p;
            a0.x = a0.x * scale + p * B2F_LO(va.x); a0.y = a0.y * scale + p * B2F_HI(va.x);
            a0.z = a0.z * scale + p * B2F_LO(va.y); a0.w = a0.w * scale + p * B2F_HI(va.y);
            a1.x = a1.x * scale + p * B2F_LO(va.z); a1.y = a1.y * scale + p * B2F_HI(va.z);
            a1.z = a1.z * scale + p * B2F_LO(va.w); a1.w = a1.w * scale + p * B2F_HI(va.w);
            a2.x = a2.x * scale + p * B2F_LO(vb.x); a2.y = a2.y * scale + p * B2F_HI(vb.x);
            a2.z = a2.z * scale + p * B2F_LO(vb.y); a2.w = a2.w * scale + p * B2F_HI(vb.y);
            a3.x = a3.x * scale + p * B2F_LO(vb.z); a3.y = a3.y * scale + p * B2F_HI(vb.z);
            a3.z = a3.z * scale + p * B2F_LO(vb.w); a3.w = a3.w * scale + p * B2F_HI(vb.w);
            m = nm;
            ka = na; kb = nb; va = nc; vb = nd;     // shift pipeline
            na = fa; nb = fb; nc = fc; nd = fd;
        }
    }
    // ---- merge the four quarter-streams (exact in fp32): xor 8, then 16 ----
    #pragma unroll
    for (int o = 8; o <= 16; o <<= 1) {
        const float mp = __shfl_xor(m, o);
        const float dp = __shfl_xor(d, o);
        const float mc = fmaxf(fmaxf(m, mp), -1e30f);  // -1e30 guard: empty-stream NaN
        const float s0 = __expf(m - mc);
        const float s1 = __expf(mp - mc);
        d = d * s0 + dp * s1;
        float pa;
        pa = __shfl_xor(a0.x, o); a0.x = a0.x * s0 + pa * s1;
        pa = __shfl_xor(a0.y, o); a0.y = a0.y * s0 + pa * s1;
        pa = __shfl_xor(a0.z, o); a0.z = a0.z * s0 + pa * s1;
        pa = __shfl_xor(a0.w, o); a0.w = a0.w * s0 + pa * s1;
        pa = __shfl_xor(a1.x, o); a1.x = a1.x * s0 + pa * s1;
        pa = __shfl_xor(a1.y, o); a1.y = a1.y * s0 + pa * s1;
        pa = __shfl_xor(a1.z, o); a1.z = a1.z * s0 + pa * s1;
        pa = __shfl_xor(a1.w, o); a1.w = a1.w * s0 + pa * s1;
        pa = __shfl_xor(a2.x, o); a2.x = a2.x * s0 + pa * s1;
        pa = __shfl_xor(a2.y, o); a2.y = a2.y * s0 + pa * s1;
        pa = __shfl_xor(a2.z, o); a2.z = a2.z * s0 + pa * s1;
        pa = __shfl_xor(a2.w, o); a2.w = a2.w * s0 + pa * s1;
        pa = __shfl_xor(a3.x, o); a3.x = a3.x * s0 + pa * s1;
        pa = __shfl_xor(a3.y, o); a3.y = a3.y * s0 + pa * s1;
        pa = __shfl_xor(a3.z, o); a3.z = a3.z * s0 + pa * s1;
        pa = __shfl_xor(a3.w, o); a3.w = a3.w * s0 + pa * s1;
        m = mc;
    }
    if (quarter == 0) {
        const float inv = 1.f / (d + 1e-16f);
        float4* op = (float4*)(xio + (size_t)n * 128 + h * 16);
        float4 o0 = op[0], o1 = op[1], o2 = op[2], o3 = op[3];
        o0.x += a0.x * inv; o0.y += a0.y * inv; o0.z += a0.z * inv; o0.w += a0.w * inv;
        o1.x += a1.x * inv; o1.y += a1.y * inv; o1.z += a1.z * inv; o1.w += a1.w * inv;
        o2.x += a2.x * inv; o2.y += a2.y * inv; o2.z += a2.z * inv; o2.w += a2.w * inv;
        o3.x += a3.x * inv; o3.y += a3.y * inv; o3.z += a3.z * inv; o3.w += a3.w * inv;
        op[0] = o0; op[1] = o1; op[2] = o2; op[3] = o3;
    }
}

// ---------------------------------------------------------------- readout (2-phase, fused gate)
__global__ __launch_bounds__(128)
void pool_partial(const float* __restrict__ x, const float* __restrict__ wg,
                  const float* __restrict__ bg, const int* __restrict__ starts,
                  float* __restrict__ psum, float* __restrict__ pmax) {
    const int g  = blockIdx.x / PCH;
    const int ch = blockIdx.x % PCH;
    const int c  = threadIdx.x;
    const int s0 = starts[g], s1 = starts[g + 1];
    const int total = s1 - s0;
    const int len = (total + PCH - 1) / PCH;
    const int n0 = s0 + ch * len;
    const int n1 = min(n0 + len, s1);
    const float w = wg[c];
    const float b = bg[0];
    __shared__ float red[2];
    float sum = 0.f, mx = -__builtin_inff();
    for (int n = n0; n < n1; ++n) {
        const float xv = x[n * 128 + c];
        float p = xv * w;
        #pragma unroll
        for (int o = 32; o; o >>= 1) p += __shfl_xor(p, o);
        if ((c & 63) == 0) red[c >> 6] = p;
        __syncthreads();
        const float dot = red[0] + red[1];
        __syncthreads();
        const float score = 1.f / (1.f + __expf(-(dot + b)));
        sum += score * xv;
        mx = fmaxf(mx, xv);
    }
    psum[blockIdx.x * 128 + c] = sum;
    pmax[blockIdx.x * 128 + c] = mx;
}

__global__ __launch_bounds__(128)
void pool_final(const float* __restrict__ psum, const float* __restrict__ pmax,
                float* __restrict__ out) {
    const int g = blockIdx.x, c = threadIdx.x;
    float s = 0.f, m = -__builtin_inff();
    #pragma unroll
    for (int ch = 0; ch < PCH; ++ch) {
        s += psum[(g * PCH + ch) * 128 + c];
        m = fmaxf(m, pmax[(g * PCH + ch) * 128 + c]);
    }
    out[g * 256 + c] = s;
    out[g * 256 + 128 + c] = m;
}

// ---------------------------------------------------------------- launch
extern "C" void kernel_launch(void* const* d_in, const int* in_sizes, int n_in,
                              void* d_out, int out_size, void* d_ws, size_t ws_size,
                              hipStream_t stream) {
    const float* x     = (const float*)d_in[0];
    const int*   ei    = (const int*)d_in[1];
    const int*   batch = (const int*)d_in[2];
    const float* Wq = (const float*)d_in[3];
    const float* bq = (const float*)d_in[4];
    const float* Wk = (const float*)d_in[5];
    const float* bk = (const float*)d_in[6];
    const float* Wv = (const float*)d_in[7];
    const float* bv = (const float*)d_in[8];
    const float* Ws = (const float*)d_in[9];
    const float* bs = (const float*)d_in[10];
    const float* wg = (const float*)d_in[11];
    const float* bg = (const float*)d_in[12];
    float* out = (float*)d_out;

    char* w = (char*)d_ws;
    unsigned short* qbf  = (unsigned short*)w; w += (size_t)NN * 128 * 2;
    unsigned short* kvb  = (unsigned short*)w; w += (size_t)NN * 256 * 2;
    float* bufA          = (float*)w;          w += (size_t)NN * 128 * 4;
    float* bufB          = (float*)w;          w += (size_t)NN * 128 * 4;
    float* psum          = (float*)w;          w += (size_t)GG * PCH * 128 * 4;
    float* pmax          = (float*)w;          w += (size_t)GG * PCH * 128 * 4;
    unsigned short* wfh  = (unsigned short*)w; w += (size_t)12 * 16384 * 2;
    unsigned short* wfl  = (unsigned short*)w; w += (size_t)12 * 16384 * 2;
    // zero-region: counts | cursor | gcur  (one memset)
    int* counts          = (int*)w;            w += (size_t)NN * 4;
    int* cursor          = (int*)w;            w += (size_t)NN * 4;
    int* gcur            = (int*)w;            w += (size_t)64 * 4;
    const size_t zero_bytes = (size_t)(NN + NN + 64) * 4;
    int* offsets         = (int*)w;            w += (size_t)NN * 4;
    int* csrc            = (int*)w;            w += (size_t)EE * 4;
    int* starts          = (int*)w;            w += (size_t)(GG + 1) * 4;

    const int* srcI = ei;
    const int* dstI = ei + EE;

    // CSR + weight prep
    hipMemsetAsync(counts, 0, zero_bytes, stream);
    hist_kernel<<<(EE + 255) / 256, 256, 0, stream>>>(dstI, counts);
    node_prep<<<SCB, 256, 0, stream>>>(counts, offsets, gcur, batch, starts);
    scatter_kernel<<<(EE + 255) / 256, 256, 0, stream>>>(srcI, dstI, offsets, cursor, csrc);
    prep_weights<<<dim3(12, 8), 256, 0, stream>>>(Wq, Wk, Wv, Ws, wfh, wfl);

    const float* xin = x;
    float* bufs[2] = {bufA, bufB};
    const int gemmBlocks = (NN + 63) / 64;   // 782
    const int attnBlocks = NN / 8;           // 6250, exact
    for (int l = 0; l < 3; ++l) {
        float* xs = bufs[l & 1];
        gemm_mfma<<<gemmBlocks, 256, 0, stream>>>(
            xin, wfh + (size_t)l * 4 * 16384, wfl + (size_t)l * 4 * 16384,
            bq + (size_t)l * 128, bk + (size_t)l * 128,
            bv + (size_t)l * 128, bs + (size_t)l * 128,
            qbf, kvb, xs);
        attn_kernel<<<attnBlocks, 256, 0, stream>>>(qbf, (const uint4*)kvb, xs, offsets, counts, csrc);
        xin = xs;
    }

    pool_partial<<<GG * PCH, 128, 0, stream>>>(xin, wg, bg, starts, psum, pmax);
    pool_final<<<GG, 128, 0, stream>>>(psum, pmax, out);
}